// Round 6
// baseline (609.310 us; speedup 1.0000x reference)
//
#include <hip/hip_runtime.h>

#define TT 64
#define CC 384
#define NH 6
#define HID 1536
#define LDX 392   // padded cols for 64x384 bf16 tiles
#define LDH 72    // head tiles (144B stride)
#define LDM 200   // mlp h-chunk (192+8)

typedef __bf16 bf16x8 __attribute__((ext_vector_type(8)));
typedef float f32x4 __attribute__((ext_vector_type(4)));
typedef unsigned short us8 __attribute__((ext_vector_type(8)));

#define MFMA(a, b, c) __builtin_amdgcn_mfma_f32_16x16x32_bf16(a, b, c, 0, 0, 0)

static __device__ __forceinline__ unsigned short f2bf(float f) {
  unsigned u = __builtin_bit_cast(unsigned, f);
  u += 0x7FFFu + ((u >> 16) & 1u);
  return (unsigned short)(u >> 16);
}
static __device__ __forceinline__ float bf2f(unsigned short h) {
  unsigned u = ((unsigned)h) << 16;
  return __builtin_bit_cast(float, u);
}
static __device__ __forceinline__ bf16x8 ld8(const unsigned short* p) {
  return __builtin_bit_cast(bf16x8, *reinterpret_cast<const us8*>(p));
}
// non-temporal fp32 stream accessors: keep big streams OUT of L2 so weights stay resident
static __device__ __forceinline__ float ldnt(const float* p) {
  return __builtin_nontemporal_load(p);
}
static __device__ __forceinline__ void stnt(float* p, float v) {
  __builtin_nontemporal_store(v, p);
}

// ---- weight prep: fp32 -> bf16, transposed to [n][k] for MFMA B-frags ----
__global__ void prep_w(const float* __restrict__ Wq, const float* __restrict__ Wk,
                       const float* __restrict__ Wv, const float* __restrict__ Wo,
                       const float* __restrict__ W1, const float* __restrict__ W2,
                       unsigned short* __restrict__ ws) {
  const int T0 = 1152 * 384;            // Wqkv [h*192+j][k]
  const int T1 = T0 + 384 * 384;        // WoT  [n][k]
  const int T2 = T1 + 1536 * 384;       // W1T  [n][k]
  const int T3 = T2 + 384 * 1536;       // W2T  [n][k]
  for (int i = blockIdx.x * blockDim.x + threadIdx.x; i < T3; i += gridDim.x * blockDim.x) {
    float v;
    if (i < T0) {
      int n = i / 384, k = i % 384;
      int hh = n / 192, j = n % 192;
      const float* W = (j < 64) ? Wq : (j < 128) ? Wk : Wv;
      int d = (j < 64) ? j : (j < 128) ? j - 64 : j - 128;
      v = ldnt(&W[((size_t)hh * 384 + k) * 64 + d]);
    } else if (i < T1) {
      int i2 = i - T0; int n = i2 / 384, k = i2 % 384;
      v = ldnt(&Wo[(size_t)k * 384 + n]);
    } else if (i < T2) {
      int i2 = i - T1; int n = i2 / 384, k = i2 % 384;
      v = ldnt(&W1[(size_t)k * 1536 + n]);
    } else {
      int i2 = i - T2; int n = i2 / 1536, k = i2 % 1536;
      v = ldnt(&W2[(size_t)k * 384 + n]);
    }
    ws[i] = f2bf(v);
  }
}

// ---- kernel A: LN1 + attention + per-head proj accumulation + residual -> x2 (=d_out, fp32)
__global__ __launch_bounds__(256, 2)
void attn_fwd(const float* __restrict__ x,
              const float* __restrict__ ln1g, const float* __restrict__ ln1b,
              const float* __restrict__ bo,
              const unsigned short* __restrict__ Wqkv,
              const unsigned short* __restrict__ WoT,
              float* __restrict__ x2) {
  __shared__ unsigned short sXN[TT * LDX];       // xn1 (bf16)
  __shared__ unsigned short sHEAD[3 * TT * LDH]; // q | k (later att_h) | vT
  unsigned short* sQ = sHEAD;                    // q [t][d]; later P [t][s]
  unsigned short* sK = sHEAD + TT * LDH;         // k [s][d]; later att_h [t][d]
  unsigned short* sV = sHEAD + 2 * TT * LDH;     // vT [d][s]

  const int b = blockIdx.x;
  const int tid = threadIdx.x;
  const int wv = tid >> 6;
  const int ln = tid & 63;
  const int l16 = ln & 15;
  const int lg = ln >> 4;
  const float* xb = x + (size_t)b * TT * CC;
  const f32x4 Z4 = {0.f, 0.f, 0.f, 0.f};

  // ---------- LN1 (nt reads: x is streamed once) ----------
#pragma unroll 1
  for (int r = wv * 16; r < wv * 16 + 16; ++r) {
    float v[6], s = 0.f, sq = 0.f;
#pragma unroll
    for (int j = 0; j < 6; ++j) { v[j] = ldnt(&xb[r * CC + ln + 64 * j]); s += v[j]; sq += v[j] * v[j]; }
#pragma unroll
    for (int off = 32; off; off >>= 1) { s += __shfl_xor(s, off); sq += __shfl_xor(sq, off); }
    float mu = s * (1.f / CC);
    float rs = rsqrtf(sq * (1.f / CC) - mu * mu + 1e-5f);
#pragma unroll
    for (int j = 0; j < 6; ++j) {
      int c = ln + 64 * j;
      sXN[r * LDX + c] = f2bf((v[j] - mu) * rs * ln1g[c] + ln1b[c]);
    }
  }
  __syncthreads();

  // persistent proj accumulator (rows m*16+lg*4+rg, cols wv*96+c*16+l16)
  f32x4 pacc[4][6];
#pragma unroll
  for (int m = 0; m < 4; ++m)
#pragma unroll
    for (int c = 0; c < 6; ++c) pacc[m][c] = Z4;

  // Wo row pointers for this wave's 6 output c-tiles (reused every head)
  const unsigned short* prow[6];
#pragma unroll
  for (int c = 0; c < 6; ++c)
    prow[c] = WoT + (size_t)(wv * 96 + c * 16 + l16) * CC + 8 * lg;

  // ---------- head loop (rolled) ----------
#pragma unroll 1
  for (int h = 0; h < NH; ++h) {
    // ----- qkv = xn @ Wh : 64 x 192, wave stripe cols [48*wv, 48*wv+48)
    const unsigned short* wrow[3];
#pragma unroll
    for (int c = 0; c < 3; ++c)
      wrow[c] = Wqkv + (size_t)(h * 192 + wv * 48 + c * 16 + l16) * CC + 8 * lg;

    f32x4 qacc[4][3];
#pragma unroll
    for (int m = 0; m < 4; ++m)
#pragma unroll
      for (int c = 0; c < 3; ++c) qacc[m][c] = Z4;

    // depth-3 B prefetch pipeline (covers ~700cy of L3 latency)
    bf16x8 bpre[3][3];
#pragma unroll
    for (int s3 = 0; s3 < 3; ++s3)
#pragma unroll
      for (int c = 0; c < 3; ++c) bpre[s3][c] = ld8(wrow[c] + 32 * s3);
#pragma unroll
    for (int kk = 0; kk < CC; kk += 32) {
      const int slot = (kk >> 5) % 3;
      bf16x8 bcur[3];
#pragma unroll
      for (int c = 0; c < 3; ++c) bcur[c] = bpre[slot][c];
      if (kk + 96 < CC) {
#pragma unroll
        for (int c = 0; c < 3; ++c) bpre[slot][c] = ld8(wrow[c] + kk + 96);
      }
      bf16x8 a[4];
#pragma unroll
      for (int m = 0; m < 4; ++m)
        a[m] = ld8(&sXN[(m * 16 + l16) * LDX + kk + 8 * lg]);
      __builtin_amdgcn_s_setprio(1);
#pragma unroll
      for (int c = 0; c < 3; ++c)
#pragma unroll
        for (int m = 0; m < 4; ++m) qacc[m][c] = MFMA(a[m], bcur[c], qacc[m][c]);
      __builtin_amdgcn_s_setprio(0);
    }
    __syncthreads();  // B1: prior head's proj reads of sK / PV reads of sV done
    // scatter: q [t][d], k [s][d], vT [d][s]
#pragma unroll
    for (int m = 0; m < 4; ++m)
#pragma unroll
      for (int c = 0; c < 3; ++c) {
        int n = wv * 48 + c * 16 + l16;
#pragma unroll
        for (int rg = 0; rg < 4; ++rg) {
          int t = m * 16 + lg * 4 + rg;
          unsigned short bv = f2bf(qacc[m][c][rg]);
          if (n < 64) sQ[t * LDH + n] = bv;
          else if (n < 128) sK[t * LDH + (n - 64)] = bv;
          else sV[(n - 128) * LDH + t] = bv;
        }
      }
    __syncthreads();  // B2

    // ----- S = q.kT for this wave's 16 rows
    f32x4 sacc[4];
#pragma unroll
    for (int c = 0; c < 4; ++c) sacc[c] = Z4;
#pragma unroll
    for (int kk = 0; kk < 64; kk += 32) {
      bf16x8 a = ld8(&sQ[(wv * 16 + l16) * LDH + kk + 8 * lg]);
#pragma unroll
      for (int c = 0; c < 4; ++c) {
        bf16x8 bb = ld8(&sK[(c * 16 + l16) * LDH + kk + 8 * lg]);
        sacc[c] = MFMA(a, bb, sacc[c]);
      }
    }
    // causal softmax (rows in 16-lane groups), P overlays q (own rows)
#pragma unroll
    for (int rg = 0; rg < 4; ++rg) {
      int row = wv * 16 + lg * 4 + rg;
      float e[4], mx = -1e30f;
#pragma unroll
      for (int c = 0; c < 4; ++c) {
        int col = c * 16 + l16;
        float vv = sacc[c][rg] * 0.125f;
        e[c] = (col <= row) ? vv : -1e30f;
        mx = fmaxf(mx, e[c]);
      }
#pragma unroll
      for (int off = 8; off; off >>= 1) mx = fmaxf(mx, __shfl_xor(mx, off));
      float sum = 0.f;
#pragma unroll
      for (int c = 0; c < 4; ++c) {
        int col = c * 16 + l16;
        e[c] = (col <= row) ? __expf(e[c] - mx) : 0.f;
        sum += e[c];
      }
#pragma unroll
      for (int off = 8; off; off >>= 1) sum += __shfl_xor(sum, off);
      float inv = 1.f / sum;
#pragma unroll
      for (int c = 0; c < 4; ++c)
        sQ[row * LDH + c * 16 + l16] = f2bf(e[c] * inv);
    }

    // Preload ALL Wo B-frags for this head NOW (12 x 16B); latency hides under PV.
    bf16x8 pb[2][6];
#pragma unroll
    for (int s2 = 0; s2 < 2; ++s2)
#pragma unroll
      for (int c = 0; c < 6; ++c)
        pb[s2][c] = ld8(prow[c] + h * 64 + 32 * s2);

    // ----- out_h = P @ V (own 16 rows); same-wave LDS ops are ordered
    f32x4 oacc[4];
#pragma unroll
    for (int c = 0; c < 4; ++c) oacc[c] = Z4;
#pragma unroll
    for (int kk = 0; kk < 64; kk += 32) {
      bf16x8 a = ld8(&sQ[(wv * 16 + l16) * LDH + kk + 8 * lg]);
#pragma unroll
      for (int c = 0; c < 4; ++c) {
        bf16x8 bb = ld8(&sV[(c * 16 + l16) * LDH + kk + 8 * lg]);
        oacc[c] = MFMA(a, bb, oacc[c]);
      }
    }
    __syncthreads();  // B3: all waves done reading sK (S phase)
    // stage att_h into sK region [t][d]
#pragma unroll
    for (int c = 0; c < 4; ++c)
#pragma unroll
      for (int rg = 0; rg < 4; ++rg) {
        int t = wv * 16 + lg * 4 + rg;
        sK[t * LDH + c * 16 + l16] = f2bf(oacc[c][rg]);
      }
    __syncthreads();  // B4: att_h visible

    // ----- proj accumulate: pacc += att_h @ WoT[:, h*64 .. h*64+63] (B already in regs)
    __builtin_amdgcn_s_setprio(1);
#pragma unroll
    for (int kk = 0; kk < 64; kk += 32) {
      const int slot = kk >> 5;
      bf16x8 a[4];
#pragma unroll
      for (int m = 0; m < 4; ++m)
        a[m] = ld8(&sK[(m * 16 + l16) * LDH + kk + 8 * lg]);
#pragma unroll
      for (int c = 0; c < 6; ++c)
#pragma unroll
        for (int m = 0; m < 4; ++m) pacc[m][c] = MFMA(a[m], pb[slot][c], pacc[m][c]);
    }
    __builtin_amdgcn_s_setprio(0);
  }

  // ---------- x2 = x + proj + bo (fp32, nt stream to d_out) ----------
  float* xo = x2 + (size_t)b * TT * CC;
#pragma unroll
  for (int m = 0; m < 4; ++m)
#pragma unroll
    for (int c = 0; c < 6; ++c) {
      int n = wv * 96 + c * 16 + l16;
      float bov = bo[n];
#pragma unroll
      for (int rg = 0; rg < 4; ++rg) {
        int t = m * 16 + lg * 4 + rg;
        stnt(&xo[t * CC + n], ldnt(&xb[t * CC + n]) + pacc[m][c][rg] + bov);
      }
    }
}

// ---- kernel B: LN2 + MLP + residual; x2 lives in d_out, overwritten in place ----
__global__ __launch_bounds__(256, 2)
void mlp_fwd(const float* __restrict__ ln2g, const float* __restrict__ ln2b,
             const float* __restrict__ b1, const float* __restrict__ b2,
             const unsigned short* __restrict__ W1T,
             const unsigned short* __restrict__ W2T,
             float* xo) {
  __shared__ unsigned short sXN[TT * LDX];  // xn2 (bf16)
  __shared__ unsigned short sH[TT * LDM];   // relu(h) chunk (bf16)

  const int b = blockIdx.x;
  const int tid = threadIdx.x;
  const int wv = tid >> 6;
  const int ln = tid & 63;
  const int l16 = ln & 15;
  const int lg = ln >> 4;
  float* xb = xo + (size_t)b * TT * CC;  // x2 rows (read-then-overwrite)
  const f32x4 Z4 = {0.f, 0.f, 0.f, 0.f};

  // ---------- LN2 (nt reads: x2 is streamed) ----------
#pragma unroll 1
  for (int r = wv * 16; r < wv * 16 + 16; ++r) {
    float v[6], s = 0.f, sq = 0.f;
#pragma unroll
    for (int j = 0; j < 6; ++j) { v[j] = ldnt(&xb[r * CC + ln + 64 * j]); s += v[j]; sq += v[j] * v[j]; }
#pragma unroll
    for (int off = 32; off; off >>= 1) { s += __shfl_xor(s, off); sq += __shfl_xor(sq, off); }
    float mu = s * (1.f / CC);
    float rs = rsqrtf(sq * (1.f / CC) - mu * mu + 1e-5f);
#pragma unroll
    for (int j = 0; j < 6; ++j) {
      int c = ln + 64 * j;
      sXN[r * LDX + c] = f2bf((v[j] - mu) * rs * ln2g[c] + ln2b[c]);
    }
  }
  __syncthreads();

  // ---------- MLP: 8 chunks of 192 hidden cols (rolled chunk loop) ----------
  f32x4 macc[4][6];
#pragma unroll
  for (int m = 0; m < 4; ++m)
#pragma unroll
    for (int c = 0; c < 6; ++c) macc[m][c] = Z4;

  // W2 row pointers for this wave's 6 output c-tiles
  const unsigned short* w2row[6];
#pragma unroll
  for (int c = 0; c < 6; ++c)
    w2row[c] = W2T + (size_t)(wv * 96 + c * 16 + l16) * HID + 8 * lg;

#pragma unroll 1
  for (int ch = 0; ch < 8; ++ch) {
    // ----- GEMM1: h = relu(xn2 @ W1 + b1), wave stripe 48 cols of 192-chunk
    const unsigned short* w1row[3];
#pragma unroll
    for (int c = 0; c < 3; ++c)
      w1row[c] = W1T + (size_t)(ch * 192 + wv * 48 + c * 16 + l16) * CC + 8 * lg;

    f32x4 hacc[4][3];
#pragma unroll
    for (int m = 0; m < 4; ++m)
#pragma unroll
      for (int c = 0; c < 3; ++c) hacc[m][c] = Z4;

    // depth-3 B prefetch
    bf16x8 bpre[3][3];
#pragma unroll
    for (int s3 = 0; s3 < 3; ++s3)
#pragma unroll
      for (int c = 0; c < 3; ++c) bpre[s3][c] = ld8(w1row[c] + 32 * s3);
#pragma unroll
    for (int kk = 0; kk < CC; kk += 32) {
      const int slot = (kk >> 5) % 3;
      bf16x8 bcur[3];
#pragma unroll
      for (int c = 0; c < 3; ++c) bcur[c] = bpre[slot][c];
      if (kk + 96 < CC) {
#pragma unroll
        for (int c = 0; c < 3; ++c) bpre[slot][c] = ld8(w1row[c] + kk + 96);
      }
      bf16x8 a[4];
#pragma unroll
      for (int m = 0; m < 4; ++m)
        a[m] = ld8(&sXN[(m * 16 + l16) * LDX + kk + 8 * lg]);
      __builtin_amdgcn_s_setprio(1);
#pragma unroll
      for (int c = 0; c < 3; ++c)
#pragma unroll
        for (int m = 0; m < 4; ++m) hacc[m][c] = MFMA(a[m], bcur[c], hacc[m][c]);
      __builtin_amdgcn_s_setprio(0);
    }
    __syncthreads();  // prior GEMM2 reads of sH done
#pragma unroll
    for (int m = 0; m < 4; ++m)
#pragma unroll
      for (int c = 0; c < 3; ++c) {
        int nl = wv * 48 + c * 16 + l16;
        float b1v = b1[ch * 192 + nl];
#pragma unroll
        for (int rg = 0; rg < 4; ++rg) {
          int t = m * 16 + lg * 4 + rg;
          sH[t * LDM + nl] = f2bf(fmaxf(hacc[m][c][rg] + b1v, 0.f));
        }
      }
    __syncthreads();  // h chunk visible

    // ----- GEMM2: macc += h @ W2[ch-slice], explicit depth-2 B prefetch
    bf16x8 b2p[2][6];
#pragma unroll
    for (int s2 = 0; s2 < 2; ++s2)
#pragma unroll
      for (int c = 0; c < 6; ++c) b2p[s2][c] = ld8(w2row[c] + ch * 192 + 32 * s2);
#pragma unroll
    for (int kk = 0; kk < 192; kk += 32) {
      const int slot = (kk >> 5) & 1;
      bf16x8 bcur[6];
#pragma unroll
      for (int c = 0; c < 6; ++c) bcur[c] = b2p[slot][c];
      if (kk + 64 < 192) {
#pragma unroll
        for (int c = 0; c < 6; ++c) b2p[slot][c] = ld8(w2row[c] + ch * 192 + kk + 64);
      }
      bf16x8 a[4];
#pragma unroll
      for (int m = 0; m < 4; ++m)
        a[m] = ld8(&sH[(m * 16 + l16) * LDM + kk + 8 * lg]);
      __builtin_amdgcn_s_setprio(1);
#pragma unroll
      for (int c = 0; c < 6; ++c)
#pragma unroll
        for (int m = 0; m < 4; ++m) macc[m][c] = MFMA(a[m], bcur[c], macc[m][c]);
      __builtin_amdgcn_s_setprio(0);
    }
  }
  // ---------- out = x2 + mlp + b2 (nt read-before-write, same buffer) ----------
#pragma unroll
  for (int m = 0; m < 4; ++m)
#pragma unroll
    for (int c = 0; c < 6; ++c) {
      int n = wv * 96 + c * 16 + l16;
      float b2v = b2[n];
#pragma unroll
      for (int rg = 0; rg < 4; ++rg) {
        int t = m * 16 + lg * 4 + rg;
        size_t idx = (size_t)t * CC + n;
        float x2v = ldnt(&xb[idx]);
        stnt(&xb[idx], x2v + macc[m][c][rg] + b2v);
      }
    }
}

extern "C" void kernel_launch(void* const* d_in, const int* in_sizes, int n_in,
                              void* d_out, int out_size, void* d_ws, size_t ws_size,
                              hipStream_t stream) {
  const float* x    = (const float*)d_in[0];
  const float* ln1g = (const float*)d_in[1];
  const float* ln1b = (const float*)d_in[2];
  const float* Wq   = (const float*)d_in[3];
  const float* Wk   = (const float*)d_in[4];
  const float* Wv   = (const float*)d_in[5];
  const float* Wo   = (const float*)d_in[6];
  const float* bo   = (const float*)d_in[7];
  const float* ln2g = (const float*)d_in[8];
  const float* ln2b = (const float*)d_in[9];
  const float* W1   = (const float*)d_in[10];
  const float* b1   = (const float*)d_in[11];
  const float* W2   = (const float*)d_in[12];
  const float* b2   = (const float*)d_in[13];
  unsigned short* ws = (unsigned short*)d_ws;

  const size_t need = (size_t)(1152 * 384 + 384 * 384 + 1536 * 384 + 384 * 1536) * 2;
  if (ws_size < need) return;

  hipLaunchKernelGGL(prep_w, dim3(1024), dim3(256), 0, stream, Wq, Wk, Wv, Wo, W1, W2, ws);

  const unsigned short* Wqkv = ws;
  const unsigned short* WoT  = ws + 1152 * 384;
  const unsigned short* W1T  = WoT + 384 * 384;
  const unsigned short* W2T  = W1T + 1536 * 384;
  int nblk = in_sizes[0] / (TT * CC);

  hipLaunchKernelGGL(attn_fwd, dim3(nblk), dim3(256), 0, stream,
                     x, ln1g, ln1b, bo, Wqkv, WoT, (float*)d_out);
  hipLaunchKernelGGL(mlp_fwd, dim3(nblk), dim3(256), 0, stream,
                     ln2g, ln2b, b1, b2, W1T, W2T, (float*)d_out);
}

// Round 7
// 468.363 us; speedup vs baseline: 1.3009x; 1.3009x over previous
//
#include <hip/hip_runtime.h>

#define TT 64
#define CC 384
#define NH 6
#define HID 1536
#define LDX 392   // padded cols for 64x384 bf16 tiles
#define LDH 72    // head tiles (144B stride)
#define LDS_H 264 // mlp sH row stride (256+8)

typedef __bf16 bf16x8 __attribute__((ext_vector_type(8)));
typedef float f32x4 __attribute__((ext_vector_type(4)));
typedef unsigned short us8 __attribute__((ext_vector_type(8)));

#define MFMA(a, b, c) __builtin_amdgcn_mfma_f32_16x16x32_bf16(a, b, c, 0, 0, 0)
#define WAITVM(N) asm volatile("s_waitcnt vmcnt(" #N ")" ::: "memory")

static __device__ __forceinline__ unsigned short f2bf(float f) {
  unsigned u = __builtin_bit_cast(unsigned, f);
  u += 0x7FFFu + ((u >> 16) & 1u);
  return (unsigned short)(u >> 16);
}
static __device__ __forceinline__ float bf2f(unsigned short h) {
  unsigned u = ((unsigned)h) << 16;
  return __builtin_bit_cast(float, u);
}
static __device__ __forceinline__ bf16x8 ld8(const unsigned short* p) {
  return __builtin_bit_cast(bf16x8, *reinterpret_cast<const us8*>(p));
}
// async global->LDS, 16B per lane; lds dest = wave-uniform base + lane*16
static __device__ __forceinline__ void glds16(const unsigned short* g, unsigned short* l) {
  __builtin_amdgcn_global_load_lds(
      (const __attribute__((address_space(1))) void*)g,
      (__attribute__((address_space(3))) void*)l, 16, 0, 0);
}

// ---- weight prep: fp32 -> bf16, transposed to [n][k] for MFMA B-frags ----
__global__ void prep_w(const float* __restrict__ Wq, const float* __restrict__ Wk,
                       const float* __restrict__ Wv, const float* __restrict__ Wo,
                       const float* __restrict__ W1, const float* __restrict__ W2,
                       unsigned short* __restrict__ ws) {
  const int T0 = 1152 * 384;            // Wqkv [h*192+j][k]
  const int T1 = T0 + 384 * 384;        // WoT  [n][k]
  const int T2 = T1 + 1536 * 384;       // W1T  [n][k]
  const int T3 = T2 + 384 * 1536;       // W2T  [n][k]
  for (int i = blockIdx.x * blockDim.x + threadIdx.x; i < T3; i += gridDim.x * blockDim.x) {
    float v;
    if (i < T0) {
      int n = i / 384, k = i % 384;
      int hh = n / 192, j = n % 192;
      const float* W = (j < 64) ? Wq : (j < 128) ? Wk : Wv;
      int d = (j < 64) ? j : (j < 128) ? j - 64 : j - 128;
      v = W[((size_t)hh * 384 + k) * 64 + d];
    } else if (i < T1) {
      int i2 = i - T0; int n = i2 / 384, k = i2 % 384;
      v = Wo[(size_t)k * 384 + n];
    } else if (i < T2) {
      int i2 = i - T1; int n = i2 / 384, k = i2 % 384;
      v = W1[(size_t)k * 1536 + n];
    } else {
      int i2 = i - T2; int n = i2 / 1536, k = i2 % 1536;
      v = W2[(size_t)k * 384 + n];
    }
    ws[i] = f2bf(v);
  }
}

// ---- kernel A: LN1 + attention + per-head proj accumulation + residual -> x2 (=d_out, fp32)
__global__ __launch_bounds__(256, 2)
void attn_fwd(const float* __restrict__ x,
              const float* __restrict__ ln1g, const float* __restrict__ ln1b,
              const float* __restrict__ bo,
              const unsigned short* __restrict__ Wqkv,
              const unsigned short* __restrict__ WoT,
              float* __restrict__ x2) {
  __shared__ unsigned short sXN[TT * LDX];       // xn1 (bf16)
  __shared__ unsigned short sHEAD[3 * TT * LDH]; // q | k (later att_h) | vT
  unsigned short* sQ = sHEAD;                    // q [t][d]; later P [t][s]
  unsigned short* sK = sHEAD + TT * LDH;         // k [s][d]; later att_h [t][d]
  unsigned short* sV = sHEAD + 2 * TT * LDH;     // vT [d][s]

  const int b = blockIdx.x;
  const int tid = threadIdx.x;
  const int wv = tid >> 6;
  const int ln = tid & 63;
  const int l16 = ln & 15;
  const int lg = ln >> 4;
  const float* xb = x + (size_t)b * TT * CC;
  const f32x4 Z4 = {0.f, 0.f, 0.f, 0.f};

  // ---------- LN1 ----------
#pragma unroll 1
  for (int r = wv * 16; r < wv * 16 + 16; ++r) {
    float v[6], s = 0.f, sq = 0.f;
#pragma unroll
    for (int j = 0; j < 6; ++j) { v[j] = xb[r * CC + ln + 64 * j]; s += v[j]; sq += v[j] * v[j]; }
#pragma unroll
    for (int off = 32; off; off >>= 1) { s += __shfl_xor(s, off); sq += __shfl_xor(sq, off); }
    float mu = s * (1.f / CC);
    float rs = rsqrtf(sq * (1.f / CC) - mu * mu + 1e-5f);
#pragma unroll
    for (int j = 0; j < 6; ++j) {
      int c = ln + 64 * j;
      sXN[r * LDX + c] = f2bf((v[j] - mu) * rs * ln1g[c] + ln1b[c]);
    }
  }
  __syncthreads();

  // persistent proj accumulator (rows m*16+lg*4+rg, cols wv*96+c*16+l16)
  f32x4 pacc[4][6];
#pragma unroll
  for (int m = 0; m < 4; ++m)
#pragma unroll
    for (int c = 0; c < 6; ++c) pacc[m][c] = Z4;

  const unsigned short* prow[6];
#pragma unroll
  for (int c = 0; c < 6; ++c)
    prow[c] = WoT + (size_t)(wv * 96 + c * 16 + l16) * CC + 8 * lg;

#pragma unroll 1
  for (int h = 0; h < NH; ++h) {
    const unsigned short* wrow[3];
#pragma unroll
    for (int c = 0; c < 3; ++c)
      wrow[c] = Wqkv + (size_t)(h * 192 + wv * 48 + c * 16 + l16) * CC + 8 * lg;

    f32x4 qacc[4][3];
#pragma unroll
    for (int m = 0; m < 4; ++m)
#pragma unroll
      for (int c = 0; c < 3; ++c) qacc[m][c] = Z4;

    // depth-2 B prefetch pipeline
    bf16x8 bpre[2][3];
#pragma unroll
    for (int c = 0; c < 3; ++c) bpre[0][c] = ld8(wrow[c] + 0);
#pragma unroll
    for (int c = 0; c < 3; ++c) bpre[1][c] = ld8(wrow[c] + 32);
#pragma unroll
    for (int kk = 0; kk < CC; kk += 32) {
      const int slot = (kk >> 5) & 1;
      bf16x8 bcur[3];
#pragma unroll
      for (int c = 0; c < 3; ++c) bcur[c] = bpre[slot][c];
      if (kk + 64 < CC) {
#pragma unroll
        for (int c = 0; c < 3; ++c) bpre[slot][c] = ld8(wrow[c] + kk + 64);
      }
      bf16x8 a[4];
#pragma unroll
      for (int m = 0; m < 4; ++m)
        a[m] = ld8(&sXN[(m * 16 + l16) * LDX + kk + 8 * lg]);
#pragma unroll
      for (int c = 0; c < 3; ++c)
#pragma unroll
        for (int m = 0; m < 4; ++m) qacc[m][c] = MFMA(a[m], bcur[c], qacc[m][c]);
    }
    __syncthreads();  // B1
    // scatter: q [t][d], k [s][d], vT [d][s]
#pragma unroll
    for (int m = 0; m < 4; ++m)
#pragma unroll
      for (int c = 0; c < 3; ++c) {
        int n = wv * 48 + c * 16 + l16;
#pragma unroll
        for (int rg = 0; rg < 4; ++rg) {
          int t = m * 16 + lg * 4 + rg;
          unsigned short bv = f2bf(qacc[m][c][rg]);
          if (n < 64) sQ[t * LDH + n] = bv;
          else if (n < 128) sK[t * LDH + (n - 64)] = bv;
          else sV[(n - 128) * LDH + t] = bv;
        }
      }
    __syncthreads();  // B2

    // ----- S = q.kT
    f32x4 sacc[4];
#pragma unroll
    for (int c = 0; c < 4; ++c) sacc[c] = Z4;
#pragma unroll
    for (int kk = 0; kk < 64; kk += 32) {
      bf16x8 a = ld8(&sQ[(wv * 16 + l16) * LDH + kk + 8 * lg]);
#pragma unroll
      for (int c = 0; c < 4; ++c) {
        bf16x8 bb = ld8(&sK[(c * 16 + l16) * LDH + kk + 8 * lg]);
        sacc[c] = MFMA(a, bb, sacc[c]);
      }
    }
    // causal softmax
#pragma unroll
    for (int rg = 0; rg < 4; ++rg) {
      int row = wv * 16 + lg * 4 + rg;
      float e[4], mx = -1e30f;
#pragma unroll
      for (int c = 0; c < 4; ++c) {
        int col = c * 16 + l16;
        float vv = sacc[c][rg] * 0.125f;
        e[c] = (col <= row) ? vv : -1e30f;
        mx = fmaxf(mx, e[c]);
      }
#pragma unroll
      for (int off = 8; off; off >>= 1) mx = fmaxf(mx, __shfl_xor(mx, off));
      float sum = 0.f;
#pragma unroll
      for (int c = 0; c < 4; ++c) {
        int col = c * 16 + l16;
        e[c] = (col <= row) ? __expf(e[c] - mx) : 0.f;
        sum += e[c];
      }
#pragma unroll
      for (int off = 8; off; off >>= 1) sum += __shfl_xor(sum, off);
      float inv = 1.f / sum;
#pragma unroll
      for (int c = 0; c < 4; ++c)
        sQ[row * LDH + c * 16 + l16] = f2bf(e[c] * inv);
    }

    // Preload ALL Wo B-frags for this head (latency hides under PV)
    bf16x8 pb[2][6];
#pragma unroll
    for (int s2 = 0; s2 < 2; ++s2)
#pragma unroll
      for (int c = 0; c < 6; ++c)
        pb[s2][c] = ld8(prow[c] + h * 64 + 32 * s2);

    // ----- out_h = P @ V
    f32x4 oacc[4];
#pragma unroll
    for (int c = 0; c < 4; ++c) oacc[c] = Z4;
#pragma unroll
    for (int kk = 0; kk < 64; kk += 32) {
      bf16x8 a = ld8(&sQ[(wv * 16 + l16) * LDH + kk + 8 * lg]);
#pragma unroll
      for (int c = 0; c < 4; ++c) {
        bf16x8 bb = ld8(&sV[(c * 16 + l16) * LDH + kk + 8 * lg]);
        oacc[c] = MFMA(a, bb, oacc[c]);
      }
    }
    __syncthreads();  // B3
#pragma unroll
    for (int c = 0; c < 4; ++c)
#pragma unroll
      for (int rg = 0; rg < 4; ++rg) {
        int t = wv * 16 + lg * 4 + rg;
        sK[t * LDH + c * 16 + l16] = f2bf(oacc[c][rg]);
      }
    __syncthreads();  // B4

    // ----- proj accumulate (B in regs)
#pragma unroll
    for (int kk = 0; kk < 64; kk += 32) {
      const int slot = kk >> 5;
      bf16x8 a[4];
#pragma unroll
      for (int m = 0; m < 4; ++m)
        a[m] = ld8(&sK[(m * 16 + l16) * LDH + kk + 8 * lg]);
#pragma unroll
      for (int c = 0; c < 6; ++c)
#pragma unroll
        for (int m = 0; m < 4; ++m) pacc[m][c] = MFMA(a[m], pb[slot][c], pacc[m][c]);
    }
  }

  // ---------- x2 = x + proj + bo ----------
  float* xo = x2 + (size_t)b * TT * CC;
#pragma unroll
  for (int m = 0; m < 4; ++m)
#pragma unroll
    for (int c = 0; c < 6; ++c) {
      int n = wv * 96 + c * 16 + l16;
      float bov = bo[n];
#pragma unroll
      for (int rg = 0; rg < 4; ++rg) {
        int t = m * 16 + lg * 4 + rg;
        xo[t * CC + n] = xb[t * CC + n] + pacc[m][c][rg] + bov;
      }
    }
}

// ---- kernel B v2: LN2 + MLP + residual; 512 thr / 8 waves / 1 WG/CU.
// Weights staged per-wave via global_load_lds double-buffer + counted vmcnt.
// x2 lives in d_out, overwritten in place.
__global__ __launch_bounds__(512, 2)
void mlp_fwd(const float* __restrict__ ln2g, const float* __restrict__ ln2b,
             const float* __restrict__ b1, const float* __restrict__ b2,
             const unsigned short* __restrict__ W1T,
             const unsigned short* __restrict__ W2T,
             float* xo) {
  __shared__ unsigned short sXN[TT * LDX];    // xn2, 50.2 KB
  __shared__ unsigned short sH[TT * LDS_H];   // relu(h) 256-chunk, 33.8 KB
  __shared__ unsigned short sW[8 * 4096];     // per-wave weight dbuf, 64 KB

  const int b = blockIdx.x;
  const int tid = threadIdx.x;
  const int wv = tid >> 6;      // 0..7
  const int ln = tid & 63;
  const int l16 = ln & 15;
  const int lg = ln >> 4;
  float* xb = xo + (size_t)b * TT * CC;
  const f32x4 Z4 = {0.f, 0.f, 0.f, 0.f};
  unsigned short* myW = sW + (wv << 12);  // 4096 elems (8 KB) per wave

  // ---------- LN2: 8 waves x 8 rows ----------
#pragma unroll 1
  for (int r = wv * 8; r < wv * 8 + 8; ++r) {
    float v[6], s = 0.f, sq = 0.f;
#pragma unroll
    for (int j = 0; j < 6; ++j) { v[j] = xb[r * CC + ln + 64 * j]; s += v[j]; sq += v[j] * v[j]; }
#pragma unroll
    for (int off = 32; off; off >>= 1) { s += __shfl_xor(s, off); sq += __shfl_xor(sq, off); }
    float mu = s * (1.f / CC);
    float rs = rsqrtf(sq * (1.f / CC) - mu * mu + 1e-5f);
#pragma unroll
    for (int j = 0; j < 6; ++j) {
      int c = ln + 64 * j;
      sXN[r * LDX + c] = f2bf((v[j] - mu) * rs * ln2g[c] + ln2b[c]);
    }
  }
  __syncthreads();

  // staging address precompute (lane-constant parts)
  // W1 slice tile [32 rows][64 k] per wave: row_l = j*8 + (ln>>3), kp0 = ((ln&7)^(ln>>3))*8
  const int w1_row = (wv << 5) + (ln >> 3);
  const int w1_kp0 = (((ln & 7) ^ (ln >> 3)) << 3);
  // W2 slice tile [48 rows][32 k] per wave: row_l = j*16 + (ln>>2), kp0 = ((ln&3)^((ln>>3)&3))*8
  const int w2_row = wv * 48 + (ln >> 2);
  const int w2_kp0 = ((((ln & 3) ^ ((ln >> 3) & 3))) << 3);

  f32x4 macc[4][3];
#pragma unroll
  for (int m = 0; m < 4; ++m)
#pragma unroll
    for (int c = 0; c < 3; ++c) macc[m][c] = Z4;

#pragma unroll 1
  for (int ch = 0; ch < 6; ++ch) {
    // ================= GEMM1: hacc = xn2 @ W1[:, ch*256 .. +256) =================
    f32x4 hacc[4][2];
#pragma unroll
    for (int m = 0; m < 4; ++m)
#pragma unroll
      for (int c = 0; c < 2; ++c) hacc[m][c] = Z4;

    // stage slice 0 -> buf 0   (safe: own region, own prior reads retired)
    {
      const unsigned short* g = W1T + (size_t)(ch * 256 + w1_row) * CC + 0 * 64 + w1_kp0;
      unsigned short* d = myW + 0 * 2048;
#pragma unroll
      for (int j = 0; j < 4; ++j) glds16(g + (size_t)(j * 8) * CC, d + (j << 9));
    }
    int cb = 0;
#pragma unroll 1
    for (int s = 0; s < 6; ++s) {
      if (s < 5) {
        const unsigned short* g = W1T + (size_t)(ch * 256 + w1_row) * CC + (s + 1) * 64 + w1_kp0;
        unsigned short* d = myW + (cb ^ 1) * 2048;
#pragma unroll
        for (int j = 0; j < 4; ++j) glds16(g + (size_t)(j * 8) * CC, d + (j << 9));
        WAITVM(4);   // slice s complete (its 4 loads are oldest)
      } else {
        WAITVM(0);
      }
#pragma unroll
      for (int kk2 = 0; kk2 < 2; ++kk2) {
        bf16x8 a[4];
#pragma unroll
        for (int m = 0; m < 4; ++m)
          a[m] = ld8(&sXN[(m * 16 + l16) * LDX + s * 64 + kk2 * 32 + 8 * lg]);
#pragma unroll
        for (int c = 0; c < 2; ++c) {
          int rloc = (c << 4) + l16;
          bf16x8 bb = ld8(&myW[cb * 2048 + rloc * 64 + ((kk2 * 32 + 8 * lg) ^ ((l16 & 7) << 3))]);
#pragma unroll
          for (int m = 0; m < 4; ++m) hacc[m][c] = MFMA(a[m], bb, hacc[m][c]);
        }
      }
      cb ^= 1;
    }
    __syncthreads();  // #1: all waves done GEMM1(ch) => all done reading sH(ch-1)

    // stage W2 slice 0 early (own region; all waves past GEMM1 => region free)
    {
      const unsigned short* g = W2T + (size_t)w2_row * HID + ch * 256 + 0 * 32 + w2_kp0;
      unsigned short* d = myW + 0 * 1536;
#pragma unroll
      for (int j = 0; j < 3; ++j) glds16(g + (size_t)(j * 16) * HID, d + (j << 9));
    }
    // write sH = relu(hacc + b1)
#pragma unroll
    for (int m = 0; m < 4; ++m)
#pragma unroll
      for (int c = 0; c < 2; ++c) {
        int nl = (wv << 5) + (c << 4) + l16;
        float b1v = b1[ch * 256 + nl];
#pragma unroll
        for (int rg = 0; rg < 4; ++rg) {
          int t = m * 16 + lg * 4 + rg;
          sH[t * LDS_H + nl] = f2bf(fmaxf(hacc[m][c][rg] + b1v, 0.f));
        }
      }
    __syncthreads();  // #2: sH visible; also drains vmcnt -> W2 slice0 ready

    // ================= GEMM2: macc += relu_h @ W2[ch-slice] =================
    cb = 0;
#pragma unroll 1
    for (int s = 0; s < 8; ++s) {
      if (s < 7) {
        const unsigned short* g = W2T + (size_t)w2_row * HID + ch * 256 + (s + 1) * 32 + w2_kp0;
        unsigned short* d = myW + (cb ^ 1) * 1536;
#pragma unroll
        for (int j = 0; j < 3; ++j) glds16(g + (size_t)(j * 16) * HID, d + (j << 9));
        WAITVM(3);
      } else {
        WAITVM(0);
      }
      bf16x8 a[4];
#pragma unroll
      for (int m = 0; m < 4; ++m)
        a[m] = ld8(&sH[(m * 16 + l16) * LDS_H + s * 32 + 8 * lg]);
#pragma unroll
      for (int c = 0; c < 3; ++c) {
        int rloc = (c << 4) + l16;
        bf16x8 bb = ld8(&myW[cb * 1536 + rloc * 32 + ((8 * lg) ^ (((rloc >> 1) & 3) << 3))]);
#pragma unroll
        for (int m = 0; m < 4; ++m) macc[m][c] = MFMA(a[m], bb, macc[m][c]);
      }
      cb ^= 1;
    }
    // loop back: next chunk's W1 staging writes only this wave's region (safe)
  }

  // ---------- out = x2 + mlp + b2 (read-before-write, same buffer) ----------
#pragma unroll
  for (int m = 0; m < 4; ++m)
#pragma unroll
    for (int c = 0; c < 3; ++c) {
      int n = wv * 48 + c * 16 + l16;
      float b2v = b2[n];
#pragma unroll
      for (int rg = 0; rg < 4; ++rg) {
        int t = m * 16 + lg * 4 + rg;
        size_t idx = (size_t)t * CC + n;
        float x2v = xb[idx];
        xb[idx] = x2v + macc[m][c][rg] + b2v;
      }
    }
}

extern "C" void kernel_launch(void* const* d_in, const int* in_sizes, int n_in,
                              void* d_out, int out_size, void* d_ws, size_t ws_size,
                              hipStream_t stream) {
  const float* x    = (const float*)d_in[0];
  const float* ln1g = (const float*)d_in[1];
  const float* ln1b = (const float*)d_in[2];
  const float* Wq   = (const float*)d_in[3];
  const float* Wk   = (const float*)d_in[4];
  const float* Wv   = (const float*)d_in[5];
  const float* Wo   = (const float*)d_in[6];
  const float* bo   = (const float*)d_in[7];
  const float* ln2g = (const float*)d_in[8];
  const float* ln2b = (const float*)d_in[9];
  const float* W1   = (const float*)d_in[10];
  const float* b1   = (const float*)d_in[11];
  const float* W2   = (const float*)d_in[12];
  const float* b2   = (const float*)d_in[13];
  unsigned short* ws = (unsigned short*)d_ws;

  const size_t need = (size_t)(1152 * 384 + 384 * 384 + 1536 * 384 + 384 * 1536) * 2;
  if (ws_size < need) return;

  hipLaunchKernelGGL(prep_w, dim3(1024), dim3(256), 0, stream, Wq, Wk, Wv, Wo, W1, W2, ws);

  const unsigned short* Wqkv = ws;
  const unsigned short* WoT  = ws + 1152 * 384;
  const unsigned short* W1T  = WoT + 384 * 384;
  const unsigned short* W2T  = W1T + 1536 * 384;
  int nblk = in_sizes[0] / (TT * CC);

  hipLaunchKernelGGL(attn_fwd, dim3(nblk), dim3(256), 0, stream,
                     x, ln1g, ln1b, bo, Wqkv, WoT, (float*)d_out);
  hipLaunchKernelGGL(mlp_fwd, dim3(nblk), dim3(512), 0, stream,
                     ln2g, ln2b, b1, b2, W1T, W2T, (float*)d_out);
}